// Round 1
// baseline (541.553 us; speedup 1.0000x reference)
//
#include <hip/hip_runtime.h>
#include <hip/hip_bf16.h>
#include <cstdint>

#define I_ 16
#define T_ 64
#define Q_ 197
#define K_ 30
#define H_ 8
#define D_ 64
#define E_ 512

static constexpr float INV_SQRT_E = 0.044194173824159216f;  // 1/sqrt(512)
static constexpr float NEGF = -3.4028234663852886e38f;       // finfo(f32).min
static constexpr float MASKEDV = NEGF * INV_SQRT_E;          // ~ -1.504e37 (no overflow)

// workspace offsets (in floats)
#define OFF_Q     0          // [I,Q,H,D]  1,613,824
#define OFF_K     1613824    // [T,K,H,D]    983,040
#define OFF_V     2596864    // [T,K,H,D]    983,040
#define OFF_TV    3579904    // [I,Q,H,D]  1,613,824
#define OFF_ASUM  5193728    // [I,T,H,K]    245,760
#define OFF_TASUM 5439488    // [I,T,H,Q]  1,613,824
#define OFF_POUT  7053312    // [I,T,E]      524,288
#define OFF_PTXT  7577600    // [I,T,E]      524,288

// ---------------- K1: per-head projections q,k,v,tv ----------------
__global__ __launch_bounds__(512) void proj_kernel(
    const float* __restrict__ image, const float* __restrict__ text,
    const float* __restrict__ Wq, const float* __restrict__ Wk,
    const float* __restrict__ Wv, const float* __restrict__ Wtv,
    float* __restrict__ ws)
{
  const int NQ = I_ * Q_;   // 3152
  const int NT = T_ * K_;   // 1920
  int bb = blockIdx.x;
  const float* X; const float* W; float* Y; int row;
  if (bb < NQ)            { X = image; W = Wq;  Y = ws + OFF_Q;  row = bb; }
  else if (bb < NQ + NT)  { X = text;  W = Wk;  Y = ws + OFF_K;  row = bb - NQ; }
  else if (bb < NQ + 2*NT){ X = text;  W = Wv;  Y = ws + OFF_V;  row = bb - NQ - NT; }
  else                    { X = image; W = Wtv; Y = ws + OFF_TV; row = bb - NQ - 2*NT; }

  __shared__ float s_x[E_];
  __shared__ float s_w[D_][D_ + 1];   // +1 pad: conflict-free s_w[dout][d] reads
  int tid = threadIdx.x;
  for (int idx = tid; idx < D_ * D_; idx += 512) s_w[idx >> 6][idx & 63] = W[idx];
  s_x[tid] = X[(size_t)row * E_ + tid];
  __syncthreads();

  int h = tid >> 6, dout = tid & 63;
  float acc = 0.f;
  #pragma unroll
  for (int d = 0; d < D_; ++d) acc = fmaf(s_x[h * 64 + d], s_w[dout][d], acc);
  Y[(size_t)row * E_ + tid] = acc;
}

// ---------------- K2: energy + dual softmax + pooled sums ----------------
__global__ __launch_bounds__(256) void attn_kernel(
    const float* __restrict__ ws_q, const float* __restrict__ ws_k,
    const int* __restrict__ text_mask,
    float* __restrict__ attn_out, float* __restrict__ tattn_out,
    float* __restrict__ A_sum, float* __restrict__ TA_sum)
{
  int b = blockIdx.x;                  // b = ((i*T)+t)*H + h
  int h = b & 7, t = (b >> 3) & 63, i = b >> 9;
  int tid = threadIdx.x;

  __shared__ float s_k[K_][D_];                    // 7680 B
  __shared__ int   s_mask[32];
  __shared__ float s_sc[Q_ * 33];                  // 26004 B (stride 33: conflict-free rows & cols)
  __shared__ __align__(16) float s_buf[Q_ * K_];   // 23640 B
  __shared__ float s_part[8][33];
  __shared__ float s_cred[32];

  // stage K tile + mask
  for (int idx = tid; idx < K_ * D_; idx += 256) {
    int kk = idx >> 6, d = idx & 63;
    s_k[kk][d] = ws_k[((size_t)(t * K_ + kk) * H_ + h) * D_ + d];
  }
  if (tid < K_) s_mask[tid] = (tid == 0) ? 1 : text_mask[t * (K_ - 1) + tid - 1];

  // Q row into registers
  float4 qv[16];
  int qi = tid;
  if (qi < Q_) {
    const float4* qp = (const float4*)(ws_q + ((size_t)(i * Q_ + qi) * H_ + h) * D_);
    #pragma unroll
    for (int j = 0; j < 16; ++j) qv[j] = qp[j];
  }
  __syncthreads();

  // energy -> masked, scaled scores
  if (qi < Q_) {
    for (int kk = 0; kk < K_; ++kk) {
      const float4* kp = (const float4*)&s_k[kk][0];
      float acc = 0.f;
      #pragma unroll
      for (int j = 0; j < 16; ++j) {
        float4 kv = kp[j];
        acc = fmaf(qv[j].x, kv.x, acc);
        acc = fmaf(qv[j].y, kv.y, acc);
        acc = fmaf(qv[j].z, kv.z, acc);
        acc = fmaf(qv[j].w, kv.w, acc);
      }
      s_sc[qi * 33 + kk] = s_mask[kk] ? acc * INV_SQRT_E : MASKEDV;
    }
  }
  __syncthreads();

  // row softmax (over k) -> s_buf = attention tile
  if (qi < Q_) {
    float m = -3.4e38f;
    #pragma unroll
    for (int kk = 0; kk < K_; ++kk) m = fmaxf(m, s_sc[qi * 33 + kk]);
    float ssum = 0.f;
    #pragma unroll
    for (int kk = 0; kk < K_; ++kk) {
      float e = __expf(s_sc[qi * 33 + kk] - m);
      s_buf[qi * K_ + kk] = e;
      ssum += e;
    }
    float inv = 1.0f / ssum;
    #pragma unroll
    for (int kk = 0; kk < K_; ++kk) s_buf[qi * K_ + kk] *= inv;
  }
  __syncthreads();

  // column partial sums of attention (for pooled i2t) + coalesced copy-out
  {
    int r = tid >> 5, c = tid & 31;
    if (c < K_) {
      float p = 0.f;
      for (int row = r; row < Q_; row += 8) p += s_buf[row * K_ + c];
      s_part[r][c] = p;
    }
    const float2* src = (const float2*)s_buf;
    float2* dst = (float2*)(attn_out + (size_t)b * (Q_ * K_));
    for (int idx = tid; idx < (Q_ * K_) / 2; idx += 256) dst[idx] = src[idx];
  }
  __syncthreads();
  if (tid < K_) {
    float s = 0.f;
    #pragma unroll
    for (int r = 0; r < 8; ++r) s += s_part[r][tid];
    A_sum[(size_t)b * K_ + tid] = s;
  }
  __syncthreads();

  // column softmax (over q) -> s_buf = text_attention tile
  {
    int r = tid >> 5, c = tid & 31;
    if (c < K_) {
      float m = -3.4e38f;
      for (int row = r; row < Q_; row += 8) m = fmaxf(m, s_sc[row * 33 + c]);
      s_part[r][c] = m;
    }
    __syncthreads();
    if (tid < 32) {
      float m = -3.4e38f;
      #pragma unroll
      for (int r2 = 0; r2 < 8; ++r2) m = fmaxf(m, s_part[r2][tid]);
      s_cred[tid] = m;
    }
    __syncthreads();
    if (c < K_) {
      float cm = s_cred[c];
      float p = 0.f;
      for (int row = r; row < Q_; row += 8) {
        float e = __expf(s_sc[row * 33 + c] - cm);
        s_buf[row * K_ + c] = e;
        p += e;
      }
      s_part[r][c] = p;
    }
    __syncthreads();
    if (tid < 32) {
      float s = 0.f;
      #pragma unroll
      for (int r2 = 0; r2 < 8; ++r2) s += s_part[r2][tid];
      s_cred[tid] = s;
    }
    __syncthreads();
    if (c < K_) {
      float inv = 1.0f / s_cred[c];
      for (int row = r; row < Q_; row += 8) s_buf[row * K_ + c] *= inv;
    }
  }
  __syncthreads();

  // TA row sums (for pooled t2i) + coalesced copy-out
  if (qi < Q_) {
    float s = 0.f;
    #pragma unroll
    for (int kk = 0; kk < K_; ++kk) s += s_buf[qi * K_ + kk];
    TA_sum[(size_t)b * Q_ + qi] = s;
  }
  {
    const float2* src = (const float2*)s_buf;
    float2* dst = (float2*)(tattn_out + (size_t)b * (Q_ * K_));
    for (int idx = tid; idx < (Q_ * K_) / 2; idx += 256) dst[idx] = src[idx];
  }
}

// ---------------- K3: pooled PV (i2t): P_out[i,t,e] ----------------
__global__ __launch_bounds__(512) void pool_out_kernel(
    const float* __restrict__ A_sum, const float* __restrict__ ws_v,
    float* __restrict__ P_out)
{
  int bt = blockIdx.x;           // i*T + t
  int t = bt & 63;
  int tid = threadIdx.x;
  int h = tid >> 6, d = tid & 63;
  __shared__ float s_A[H_ * K_];
  if (tid < H_ * K_) s_A[tid] = A_sum[(size_t)bt * H_ * K_ + tid];
  __syncthreads();
  float acc = 0.f;
  #pragma unroll
  for (int kk = 0; kk < K_; ++kk)
    acc = fmaf(s_A[h * K_ + kk], ws_v[((size_t)(t * K_ + kk) * H_ + h) * D_ + d], acc);
  P_out[(size_t)bt * E_ + tid] = acc * (1.0f / 197.0f);
}

// ---------------- K4: pooled (t2i): P_txt[i,t,e] ----------------
__global__ __launch_bounds__(512) void pool_text_kernel(
    const float* __restrict__ TA_sum, const float* __restrict__ ws_tv,
    float* __restrict__ P_txt)
{
  int bt = blockIdx.x;           // i*T + t
  int i = bt >> 6;
  int tid = threadIdx.x;
  int h = tid >> 6, d = tid & 63;
  __shared__ float s_TA[H_ * Q_];   // 1576 floats
  for (int idx = tid; idx < H_ * Q_; idx += 512) s_TA[idx] = TA_sum[(size_t)bt * H_ * Q_ + idx];
  __syncthreads();
  float acc = 0.f;
  for (int qq = 0; qq < Q_; ++qq)
    acc = fmaf(s_TA[h * Q_ + qq], ws_tv[((size_t)(i * Q_ + qq) * H_ + h) * D_ + d], acc);
  P_txt[(size_t)bt * E_ + tid] = acc * (1.0f / 30.0f);
}

// ---------------- K5: out = A @ W^T + bias (M=1024,N=512,K=512) ----------------
__global__ __launch_bounds__(256) void outproj_kernel(
    const float* __restrict__ A, const float* __restrict__ W,
    const float* __restrict__ bias, float* __restrict__ out)
{
  int r0 = blockIdx.x * 8;
  int eo = blockIdx.y * 256 + threadIdx.x;
  __shared__ float s_A[8][E_];   // 16 KB
  for (int idx = threadIdx.x; idx < 8 * E_; idx += 256)
    s_A[idx >> 9][idx & 511] = A[(size_t)(r0 + (idx >> 9)) * E_ + (idx & 511)];
  __syncthreads();
  float acc[8] = {};
  const float4* wrow = (const float4*)(W + (size_t)eo * E_);
  for (int e4 = 0; e4 < E_ / 4; ++e4) {
    float4 w4 = wrow[e4];
    #pragma unroll
    for (int r = 0; r < 8; ++r) {
      acc[r] = fmaf(s_A[r][e4 * 4 + 0], w4.x, acc[r]);
      acc[r] = fmaf(s_A[r][e4 * 4 + 1], w4.y, acc[r]);
      acc[r] = fmaf(s_A[r][e4 * 4 + 2], w4.z, acc[r]);
      acc[r] = fmaf(s_A[r][e4 * 4 + 3], w4.w, acc[r]);
    }
  }
  float bv = bias[eo];
  #pragma unroll
  for (int r = 0; r < 8; ++r) out[(size_t)(r0 + r) * E_ + eo] = acc[r] + bv;
}

extern "C" void kernel_launch(void* const* d_in, const int* in_sizes, int n_in,
                              void* d_out, int out_size, void* d_ws, size_t ws_size,
                              hipStream_t stream)
{
  const float* image      = (const float*)d_in[0];
  const float* text       = (const float*)d_in[1];
  const int*   tmask      = (const int*)d_in[2];
  const float* Wq         = (const float*)d_in[3];
  const float* Wk         = (const float*)d_in[4];
  const float* Wv         = (const float*)d_in[5];
  const float* W_out      = (const float*)d_in[6];
  const float* b_out      = (const float*)d_in[7];
  const float* Wtv        = (const float*)d_in[8];
  const float* W_out_text = (const float*)d_in[9];
  const float* b_out_text = (const float*)d_in[10];

  float* out = (float*)d_out;
  float* ws  = (float*)d_ws;

  float* q     = ws + OFF_Q;
  float* k     = ws + OFF_K;
  float* v     = ws + OFF_V;
  float* tv    = ws + OFF_TV;
  float* Asum  = ws + OFF_ASUM;
  float* TAsum = ws + OFF_TASUM;
  float* Pout  = ws + OFF_POUT;
  float* Ptxt  = ws + OFF_PTXT;

  float* out_i2t = out;                                   // [I,T,E]
  float* out_t2i = out + (size_t)I_ * T_ * E_;            // [I,T,E]
  float* attn    = out + (size_t)2 * I_ * T_ * E_;        // [I,T,H,Q,K]
  float* tattn   = attn + (size_t)I_ * T_ * H_ * Q_ * K_; // [I,T,H,Q,K]

  proj_kernel<<<I_*Q_ + 2*(T_*K_) + I_*Q_, 512, 0, stream>>>(image, text, Wq, Wk, Wv, Wtv, ws);
  attn_kernel<<<I_ * T_ * H_, 256, 0, stream>>>(q, k, tmask, attn, tattn, Asum, TAsum);
  pool_out_kernel<<<I_ * T_, 512, 0, stream>>>(Asum, v, Pout);
  pool_text_kernel<<<I_ * T_, 512, 0, stream>>>(TAsum, tv, Ptxt);
  outproj_kernel<<<dim3(128, 2), 256, 0, stream>>>(Pout, W_out, b_out, out_i2t);
  outproj_kernel<<<dim3(128, 2), 256, 0, stream>>>(Ptxt, W_out_text, b_out_text, out_t2i);
}

// Round 3
// 356.295 us; speedup vs baseline: 1.5200x; 1.5200x over previous
//
#include <hip/hip_runtime.h>
#include <hip/hip_bf16.h>
#include <cstdint>

#define I_ 16
#define T_ 64
#define Q_ 197
#define K_ 30
#define H_ 8
#define D_ 64
#define E_ 512

typedef float f32x2 __attribute__((ext_vector_type(2)));

static constexpr float INV_SQRT_E = 0.044194173824159216f;  // 1/sqrt(512)
static constexpr float C197 = 1.0f / 197.0f;

// workspace offsets (in floats)
#define OFF_Q     0          // [I,Q,H,D]  1,613,824
#define OFF_K     1613824    // [T,K,H,D]    983,040
#define OFF_V     2596864    // [T,K,H,D]    983,040
#define OFF_TV    3579904    // [I,Q,H,D]  1,613,824
#define OFF_ASUM  5193728    // [I,T,H,K]    245,760
#define OFF_TASUM 5439488    // [I,T,H,Q]  1,613,824
#define OFF_POUT  7053312    // [I,T,E]      524,288
#define OFF_PTXT  7577600    // [I,T,E]      524,288

// ---------------- K1: per-head projections q,k,v,tv (4 rows/block) ----------------
__global__ __launch_bounds__(512) void proj_kernel(
    const float* __restrict__ image, const float* __restrict__ text,
    const float* __restrict__ Wq, const float* __restrict__ Wk,
    const float* __restrict__ Wv, const float* __restrict__ Wtv,
    float* __restrict__ ws)
{
  const int NQ4 = (I_ * Q_) / 4;   // 788
  const int NT4 = (T_ * K_) / 4;   // 480
  int bb = blockIdx.x;
  const float* X; const float* W; float* Y; int row0;
  if (bb < NQ4)             { X = image; W = Wq;  Y = ws + OFF_Q;  row0 = bb * 4; }
  else if (bb < NQ4 + NT4)  { X = text;  W = Wk;  Y = ws + OFF_K;  row0 = (bb - NQ4) * 4; }
  else if (bb < NQ4 + 2*NT4){ X = text;  W = Wv;  Y = ws + OFF_V;  row0 = (bb - NQ4 - NT4) * 4; }
  else                      { X = image; W = Wtv; Y = ws + OFF_TV; row0 = (bb - NQ4 - 2*NT4) * 4; }

  __shared__ float s_x[4][E_];        // 8 KB
  __shared__ float s_w[D_][D_ + 1];   // 16.6 KB, +1 pad
  int tid = threadIdx.x;
  for (int idx = tid; idx < D_ * D_; idx += 512) s_w[idx >> 6][idx & 63] = W[idx];
  #pragma unroll
  for (int rr = 0; rr < 4; ++rr) s_x[rr][tid] = X[(size_t)(row0 + rr) * E_ + tid];
  __syncthreads();

  int h = tid >> 6, dout = tid & 63;
  float a0 = 0.f, a1 = 0.f, a2 = 0.f, a3 = 0.f;
  #pragma unroll
  for (int d = 0; d < D_; ++d) {
    float w = s_w[dout][d];
    a0 = fmaf(s_x[0][h * 64 + d], w, a0);
    a1 = fmaf(s_x[1][h * 64 + d], w, a1);
    a2 = fmaf(s_x[2][h * 64 + d], w, a2);
    a3 = fmaf(s_x[3][h * 64 + d], w, a3);
  }
  Y[(size_t)(row0 + 0) * E_ + tid] = a0;
  Y[(size_t)(row0 + 1) * E_ + tid] = a1;
  Y[(size_t)(row0 + 2) * E_ + tid] = a2;
  Y[(size_t)(row0 + 3) * E_ + tid] = a3;
}

// ---------------- K2: energy + dual softmax (shared exp tile) + pooled sums ----------------
__global__ __launch_bounds__(256, 4) void attn_kernel(
    const float* __restrict__ ws_q, const float* __restrict__ ws_k,
    const int* __restrict__ text_mask,
    float* __restrict__ attn_out, float* __restrict__ tattn_out,
    float* __restrict__ A_sum, float* __restrict__ TA_sum)
{
  int b = blockIdx.x;                  // b = ((i*T)+t)*H + h
  int h = b & 7, t = (b >> 3) & 63, i = b >> 9;
  int tid = threadIdx.x;

  __shared__ float s_k[K_][D_];                    // 7680 B
  __shared__ int   s_mask[32];
  __shared__ __align__(16) float s_e[Q_ * K_];     // 23640 B (exp tile, masked=0)
  __shared__ float s_invrow[Q_ + 3];
  __shared__ float s_invd[32];
  __shared__ float s_pe[8][32];
  __shared__ float s_pa[8][32];

  // stage K tile + mask
  for (int idx = tid; idx < K_ * D_; idx += 256) {
    int kk = idx >> 6, d = idx & 63;
    s_k[kk][d] = ws_k[((size_t)(t * K_ + kk) * H_ + h) * D_ + d];
  }
  if (tid < 32) s_mask[tid] = (tid == 0) ? 1 : (tid < K_ ? text_mask[t * (K_ - 1) + tid - 1] : 0);
  __syncthreads();

  int qi = tid;
  float e[K_];     // per-row exp values, live across syncs
  if (qi < Q_) {
    // energy: 30 independent accumulator chains (ILP), d in 4 chunks of 16
    float acc[K_];
    #pragma unroll
    for (int kk = 0; kk < K_; ++kk) acc[kk] = 0.f;
    const float4* qp = (const float4*)(ws_q + ((size_t)(i * Q_ + qi) * H_ + h) * D_);
    for (int jj = 0; jj < 4; ++jj) {
      float4 q0 = qp[jj * 4 + 0], q1 = qp[jj * 4 + 1];
      float4 q2 = qp[jj * 4 + 2], q3 = qp[jj * 4 + 3];
      #pragma unroll
      for (int kk = 0; kk < K_; ++kk) {
        const float4* kp = (const float4*)&s_k[kk][jj * 16];
        float4 k0 = kp[0], k1 = kp[1], k2 = kp[2], k3 = kp[3];
        float a = acc[kk];
        a = fmaf(q0.x, k0.x, a); a = fmaf(q0.y, k0.y, a);
        a = fmaf(q0.z, k0.z, a); a = fmaf(q0.w, k0.w, a);
        a = fmaf(q1.x, k1.x, a); a = fmaf(q1.y, k1.y, a);
        a = fmaf(q1.z, k1.z, a); a = fmaf(q1.w, k1.w, a);
        a = fmaf(q2.x, k2.x, a); a = fmaf(q2.y, k2.y, a);
        a = fmaf(q2.z, k2.z, a); a = fmaf(q2.w, k2.w, a);
        a = fmaf(q3.x, k3.x, a); a = fmaf(q3.y, k3.y, a);
        a = fmaf(q3.z, k3.z, a); a = fmaf(q3.w, k3.w, a);
        acc[kk] = a;
      }
    }
    // no max-subtraction: scores ~ +-0.5, exp is safe; masked -> exactly 0
    float rowsum = 0.f;
    #pragma unroll
    for (int kk = 0; kk < K_; ++kk) {
      float ev = s_mask[kk] ? __expf(acc[kk] * INV_SQRT_E) : 0.f;
      e[kk] = ev;
      rowsum += ev;
    }
    float invrow = 1.0f / rowsum;   // k=0 always unmasked -> rowsum > 0
    s_invrow[qi] = invrow;
    #pragma unroll
    for (int kk = 0; kk < K_; ++kk) s_e[qi * K_ + kk] = e[kk];
  }
  __syncthreads();

  // column partial sums: d_c = sum_r e  and  A_sum_c = sum_r e*invrow_r
  {
    int r = tid >> 5, c = tid & 31;
    float pe = 0.f, pa = 0.f;
    if (c < K_) {
      for (int row = r; row < Q_; row += 8) {
        float ev = s_e[row * K_ + c];
        pe += ev;
        pa += ev * s_invrow[row];
      }
    }
    s_pe[r][c] = pe;
    s_pa[r][c] = pa;
  }
  __syncthreads();
  if (tid < K_) {
    float dsum = 0.f, asum = 0.f;
    #pragma unroll
    for (int r2 = 0; r2 < 8; ++r2) { dsum += s_pe[r2][tid]; asum += s_pa[r2][tid]; }
    s_invd[tid] = s_mask[tid] ? (1.0f / dsum) : 0.f;   // masked col: handled by C197 branch
    A_sum[(size_t)b * K_ + tid] = asum;
  }
  __syncthreads();

  // TA_sum from registers (masked col contributes exactly 1/197)
  if (qi < Q_) {
    float ta = 0.f;
    #pragma unroll
    for (int kk = 0; kk < K_; ++kk)
      ta += s_mask[kk] ? e[kk] * s_invd[kk] : C197;
    TA_sum[(size_t)b * Q_ + qi] = ta;
  }

  // fused copy-out of both tiles from the single exp tile (non-temporal)
  {
    int r0 = tid >> 4;          // 0..15
    int c2 = tid & 15;          // 0..15; active when <15 (15 float2 per 30-col row)
    if (c2 < 15) {
      int m0 = s_mask[2 * c2], m1 = s_mask[2 * c2 + 1];
      float inv0 = s_invd[2 * c2], inv1 = s_invd[2 * c2 + 1];
      f32x2* adst = (f32x2*)(attn_out + (size_t)b * (Q_ * K_));
      f32x2* tdst = (f32x2*)(tattn_out + (size_t)b * (Q_ * K_));
      for (int row = r0; row < Q_; row += 16) {
        float ex = s_e[row * K_ + 2 * c2];
        float ey = s_e[row * K_ + 2 * c2 + 1];
        float ir = s_invrow[row];
        f32x2 av = { ex * ir, ey * ir };
        f32x2 tv2 = { m0 ? ex * inv0 : C197, m1 ? ey * inv1 : C197 };
        int o = row * 15 + c2;
        __builtin_nontemporal_store(av, &adst[o]);
        __builtin_nontemporal_store(tv2, &tdst[o]);
      }
    }
  }
}

// ---------------- K3: pooled PV (i2t): P_out[i,t,e] ----------------
__global__ __launch_bounds__(512) void pool_out_kernel(
    const float* __restrict__ A_sum, const float* __restrict__ ws_v,
    float* __restrict__ P_out)
{
  int bt = blockIdx.x;           // i*T + t
  int t = bt & 63;
  int tid = threadIdx.x;
  int h = tid >> 6, d = tid & 63;
  __shared__ float s_A[H_ * K_];
  if (tid < H_ * K_) s_A[tid] = A_sum[(size_t)bt * H_ * K_ + tid];
  __syncthreads();
  float a0 = 0.f, a1 = 0.f;
  #pragma unroll
  for (int kk = 0; kk < K_; kk += 2) {
    a0 = fmaf(s_A[h * K_ + kk],     ws_v[((size_t)(t * K_ + kk)     * H_ + h) * D_ + d], a0);
    a1 = fmaf(s_A[h * K_ + kk + 1], ws_v[((size_t)(t * K_ + kk + 1) * H_ + h) * D_ + d], a1);
  }
  P_out[(size_t)bt * E_ + tid] = (a0 + a1) * (1.0f / 197.0f);
}

// ---------------- K4: pooled (t2i): P_txt[i,t,e] ----------------
__global__ __launch_bounds__(512) void pool_text_kernel(
    const float* __restrict__ TA_sum, const float* __restrict__ ws_tv,
    float* __restrict__ P_txt)
{
  int bt = blockIdx.x;           // i*T + t
  int i = bt >> 6;
  int tid = threadIdx.x;
  int h = tid >> 6, d = tid & 63;
  __shared__ float s_TA[H_ * Q_];   // 1576 floats
  for (int idx = tid; idx < H_ * Q_; idx += 512) s_TA[idx] = TA_sum[(size_t)bt * H_ * Q_ + idx];
  __syncthreads();
  float a0 = 0.f, a1 = 0.f, a2 = 0.f, a3 = 0.f;
  int qq = 0;
  for (; qq + 4 <= Q_; qq += 4) {
    a0 = fmaf(s_TA[h * Q_ + qq + 0], ws_tv[((size_t)(i * Q_ + qq + 0) * H_ + h) * D_ + d], a0);
    a1 = fmaf(s_TA[h * Q_ + qq + 1], ws_tv[((size_t)(i * Q_ + qq + 1) * H_ + h) * D_ + d], a1);
    a2 = fmaf(s_TA[h * Q_ + qq + 2], ws_tv[((size_t)(i * Q_ + qq + 2) * H_ + h) * D_ + d], a2);
    a3 = fmaf(s_TA[h * Q_ + qq + 3], ws_tv[((size_t)(i * Q_ + qq + 3) * H_ + h) * D_ + d], a3);
  }
  for (; qq < Q_; ++qq)
    a0 = fmaf(s_TA[h * Q_ + qq], ws_tv[((size_t)(i * Q_ + qq) * H_ + h) * D_ + d], a0);
  P_txt[(size_t)bt * E_ + tid] = ((a0 + a1) + (a2 + a3)) * (1.0f / 30.0f);
}

// ---------------- K5: out = A @ W^T + bias (M=1024,N=512,K=512) ----------------
__global__ __launch_bounds__(256) void outproj_kernel(
    const float* __restrict__ A, const float* __restrict__ W,
    const float* __restrict__ bias, float* __restrict__ out)
{
  int r0 = blockIdx.x * 8;
  int eo = blockIdx.y * 256 + threadIdx.x;
  __shared__ float s_A[8][E_];   // 16 KB
  for (int idx = threadIdx.x; idx < 8 * E_; idx += 256)
    s_A[idx >> 9][idx & 511] = A[(size_t)(r0 + (idx >> 9)) * E_ + (idx & 511)];
  __syncthreads();
  float acc[8] = {};
  const float4* wrow = (const float4*)(W + (size_t)eo * E_);
  for (int e4 = 0; e4 < E_ / 4; ++e4) {
    float4 w4 = wrow[e4];
    #pragma unroll
    for (int r = 0; r < 8; ++r) {
      acc[r] = fmaf(s_A[r][e4 * 4 + 0], w4.x, acc[r]);
      acc[r] = fmaf(s_A[r][e4 * 4 + 1], w4.y, acc[r]);
      acc[r] = fmaf(s_A[r][e4 * 4 + 2], w4.z, acc[r]);
      acc[r] = fmaf(s_A[r][e4 * 4 + 3], w4.w, acc[r]);
    }
  }
  float bv = bias[eo];
  #pragma unroll
  for (int r = 0; r < 8; ++r) out[(size_t)(r0 + r) * E_ + eo] = acc[r] + bv;
}

extern "C" void kernel_launch(void* const* d_in, const int* in_sizes, int n_in,
                              void* d_out, int out_size, void* d_ws, size_t ws_size,
                              hipStream_t stream)
{
  const float* image      = (const float*)d_in[0];
  const float* text       = (const float*)d_in[1];
  const int*   tmask      = (const int*)d_in[2];
  const float* Wq         = (const float*)d_in[3];
  const float* Wk         = (const float*)d_in[4];
  const float* Wv         = (const float*)d_in[5];
  const float* W_out      = (const float*)d_in[6];
  const float* b_out      = (const float*)d_in[7];
  const float* Wtv        = (const float*)d_in[8];
  const float* W_out_text = (const float*)d_in[9];
  const float* b_out_text = (const float*)d_in[10];

  float* out = (float*)d_out;
  float* ws  = (float*)d_ws;

  float* q     = ws + OFF_Q;
  float* k     = ws + OFF_K;
  float* v     = ws + OFF_V;
  float* tv    = ws + OFF_TV;
  float* Asum  = ws + OFF_ASUM;
  float* TAsum = ws + OFF_TASUM;
  float* Pout  = ws + OFF_POUT;
  float* Ptxt  = ws + OFF_PTXT;

  float* out_i2t = out;                                   // [I,T,E]
  float* out_t2i = out + (size_t)I_ * T_ * E_;            // [I,T,E]
  float* attn    = out + (size_t)2 * I_ * T_ * E_;        // [I,T,H,Q,K]
  float* tattn   = attn + (size_t)I_ * T_ * H_ * Q_ * K_; // [I,T,H,Q,K]

  proj_kernel<<<(I_*Q_)/4 + 2*((T_*K_)/4) + (I_*Q_)/4, 512, 0, stream>>>(image, text, Wq, Wk, Wv, Wtv, ws);
  attn_kernel<<<I_ * T_ * H_, 256, 0, stream>>>(q, k, tmask, attn, tattn, Asum, TAsum);
  pool_out_kernel<<<I_ * T_, 512, 0, stream>>>(Asum, v, Pout);
  pool_text_kernel<<<I_ * T_, 512, 0, stream>>>(TAsum, tv, Ptxt);
  outproj_kernel<<<dim3(128, 2), 256, 0, stream>>>(Pout, W_out, b_out, out_i2t);
  outproj_kernel<<<dim3(128, 2), 256, 0, stream>>>(Ptxt, W_out_text, b_out_text, out_t2i);
}

// Round 4
// 276.141 us; speedup vs baseline: 1.9611x; 1.2903x over previous
//
#include <hip/hip_runtime.h>
#include <hip/hip_bf16.h>
#include <cstdint>

#define I_ 16
#define T_ 64
#define Q_ 197
#define K_ 30
#define H_ 8
#define D_ 64
#define E_ 512

typedef float f32x2 __attribute__((ext_vector_type(2)));
typedef float f32x4 __attribute__((ext_vector_type(4)));
typedef short bf16x8 __attribute__((ext_vector_type(8)));

static constexpr float INV_SQRT_E = 0.044194173824159216f;  // 1/sqrt(512)
static constexpr float C197 = 1.0f / 197.0f;

// workspace offsets (in float units)
#define OFF_QBF   0          // bf16 [I,Q,H,D] 1,613,824 elems = 806,912 floats
#define OFF_KBF   806912     // bf16 [T,K,H,D]   983,040 elems = 491,520 floats
#define OFF_V     1298432    // f32  [T,K,H,D]   983,040
#define OFF_TV    2281472    // f32  [I,Q,H,D] 1,613,824
#define OFF_ASUM  3895296    // [I,T,H,K]        245,760
#define OFF_TASUM 4141056    // [I,T,H,Q]      1,613,824
#define OFF_POUT  5754880    // [I,T,E]          524,288
#define OFF_PTXT  6279168    // [I,T,E]          524,288

// ---------------- K1: projections; q,k -> bf16, v,tv -> f32 ----------------
__global__ __launch_bounds__(512) void proj_kernel(
    const float* __restrict__ image, const float* __restrict__ text,
    const float* __restrict__ Wq, const float* __restrict__ Wk,
    const float* __restrict__ Wv, const float* __restrict__ Wtv,
    float* __restrict__ ws)
{
  const int NQ4 = (I_ * Q_) / 4;   // 788
  const int NT4 = (T_ * K_) / 4;   // 480
  int bb = blockIdx.x;
  const float* X; const float* W; int row0; int mode;
  if (bb < NQ4)             { X = image; W = Wq;  row0 = bb * 4;               mode = 0; }
  else if (bb < NQ4 + NT4)  { X = text;  W = Wk;  row0 = (bb - NQ4) * 4;       mode = 1; }
  else if (bb < NQ4 + 2*NT4){ X = text;  W = Wv;  row0 = (bb - NQ4 - NT4) * 4; mode = 2; }
  else                      { X = image; W = Wtv; row0 = (bb - NQ4 - 2*NT4)*4; mode = 3; }

  __shared__ float s_x[4][E_];        // 8 KB
  __shared__ float s_w[D_][D_ + 1];   // 16.6 KB, +1 pad
  int tid = threadIdx.x;
  for (int idx = tid; idx < D_ * D_; idx += 512) s_w[idx >> 6][idx & 63] = W[idx];
  #pragma unroll
  for (int rr = 0; rr < 4; ++rr) s_x[rr][tid] = X[(size_t)(row0 + rr) * E_ + tid];
  __syncthreads();

  int h = tid >> 6, dout = tid & 63;
  float a0 = 0.f, a1 = 0.f, a2 = 0.f, a3 = 0.f;
  #pragma unroll
  for (int d = 0; d < D_; ++d) {
    float w = s_w[dout][d];
    a0 = fmaf(s_x[0][h * 64 + d], w, a0);
    a1 = fmaf(s_x[1][h * 64 + d], w, a1);
    a2 = fmaf(s_x[2][h * 64 + d], w, a2);
    a3 = fmaf(s_x[3][h * 64 + d], w, a3);
  }
  if (mode <= 1) {
    __hip_bfloat16* Y = (__hip_bfloat16*)(ws + (mode == 0 ? OFF_QBF : OFF_KBF));
    Y[(size_t)(row0 + 0) * E_ + tid] = __float2bfloat16(a0);
    Y[(size_t)(row0 + 1) * E_ + tid] = __float2bfloat16(a1);
    Y[(size_t)(row0 + 2) * E_ + tid] = __float2bfloat16(a2);
    Y[(size_t)(row0 + 3) * E_ + tid] = __float2bfloat16(a3);
  } else {
    float* Y = ws + (mode == 2 ? OFF_V : OFF_TV);
    Y[(size_t)(row0 + 0) * E_ + tid] = a0;
    Y[(size_t)(row0 + 1) * E_ + tid] = a1;
    Y[(size_t)(row0 + 2) * E_ + tid] = a2;
    Y[(size_t)(row0 + 3) * E_ + tid] = a3;
  }
}

// ---------------- K2: MFMA energy + dual softmax + pooled sums ----------------
__global__ __launch_bounds__(256, 5) void attn_kernel(
    const __hip_bfloat16* __restrict__ qbf, const __hip_bfloat16* __restrict__ kbf,
    const int* __restrict__ text_mask,
    float* __restrict__ attn_out, float* __restrict__ tattn_out,
    float* __restrict__ A_sum, float* __restrict__ TA_sum)
{
  int b = blockIdx.x;                  // b = ((i*T)+t)*H + h
  int h = b & 7, t = (b >> 3) & 63, i = b >> 9;
  int tid = threadIdx.x;

  __shared__ float s_sc[208 * 33];     // 27,456 B: raw scores, then exp tile in place
  __shared__ int   s_mask[32];
  __shared__ float s_invrow[208];
  __shared__ float s_invd[32];
  __shared__ float s_pe[8][32];
  __shared__ float s_pa[8][32];

  if (tid < 32) s_mask[tid] = (tid == 0) ? 1 : (tid < K_ ? text_mask[t * (K_ - 1) + tid - 1] : 0);

  // ---- energy via MFMA 16x16x32 bf16: S[208x32] = Q[208x64] . K^T ----
  // A lane layout: m = l&15, k = (l>>4)*8 + e (8 contiguous bf16 = 16B)
  // B lane layout: n = l&15, same k. C/D: col = l&15, row = (l>>4)*4 + reg (m89-verified)
  int wave = tid >> 6, lane = tid & 63;
  int lr = lane & 15, lg = lane >> 4;
  const __hip_bfloat16* qb = qbf + ((size_t)(i * Q_) * H_ + h) * D_;  // row stride 512
  const __hip_bfloat16* kb = kbf + ((size_t)(t * K_) * H_ + h) * D_;
  for (int tix = wave; tix < 26; tix += 4) {
    int mt = tix >> 1, nt = tix & 1;
    f32x4 acc = {0.f, 0.f, 0.f, 0.f};
    const bf16x8* ap = (const bf16x8*)(qb + (size_t)(mt * 16 + lr) * (H_ * D_) + lg * 8);
    const bf16x8* bp = (const bf16x8*)(kb + (size_t)(nt * 16 + lr) * (H_ * D_) + lg * 8);
    #pragma unroll
    for (int ks = 0; ks < 2; ++ks) {
      bf16x8 av = ap[ks * 4];    // +32 bf16 per K-step
      bf16x8 bv = bp[ks * 4];
      acc = __builtin_amdgcn_mfma_f32_16x16x32_bf16(av, bv, acc, 0, 0, 0);
    }
    int row0 = mt * 16 + lg * 4;
    int col = nt * 16 + lr;
    #pragma unroll
    for (int r = 0; r < 4; ++r) s_sc[(row0 + r) * 33 + col] = acc[r];
  }
  __syncthreads();

  // ---- row softmax (over k), exp in place; masked -> exactly 0 ----
  int qi = tid;
  if (qi < Q_) {
    float rowsum = 0.f;
    #pragma unroll
    for (int kk = 0; kk < K_; ++kk) {
      float s = s_sc[qi * 33 + kk];
      float ev = s_mask[kk] ? __expf(s * INV_SQRT_E) : 0.f;
      s_sc[qi * 33 + kk] = ev;
      rowsum += ev;
    }
    s_invrow[qi] = 1.0f / rowsum;    // k=0 always unmasked
  }
  __syncthreads();

  // ---- column partials: denom (sum e) and A_sum (sum e*invrow) ----
  {
    int r = tid >> 5, c = tid & 31;
    float pe = 0.f, pa = 0.f;
    if (c < K_) {
      for (int row = r; row < Q_; row += 8) {
        float ev = s_sc[row * 33 + c];
        pe += ev;
        pa += ev * s_invrow[row];
      }
    }
    s_pe[r][c] = pe;
    s_pa[r][c] = pa;
  }
  __syncthreads();
  if (tid < K_) {
    float dsum = 0.f, asum = 0.f;
    #pragma unroll
    for (int r2 = 0; r2 < 8; ++r2) { dsum += s_pe[r2][tid]; asum += s_pa[r2][tid]; }
    s_invd[tid] = s_mask[tid] ? (1.0f / dsum) : 0.f;
    A_sum[(size_t)b * K_ + tid] = asum;
  }
  __syncthreads();

  // ---- TA_sum (masked col contributes exactly 1/197) ----
  if (qi < Q_) {
    float ta = 0.f;
    #pragma unroll
    for (int kk = 0; kk < K_; ++kk) {
      float ev = s_sc[qi * 33 + kk];
      ta += s_mask[kk] ? ev * s_invd[kk] : C197;
    }
    TA_sum[(size_t)b * Q_ + qi] = ta;
  }

  // ---- fused non-temporal copy-out of both tiles ----
  {
    int r0 = tid >> 4;          // 0..15
    int c2 = tid & 15;          // active when <15
    if (c2 < 15) {
      int m0 = s_mask[2 * c2], m1 = s_mask[2 * c2 + 1];
      float inv0 = s_invd[2 * c2], inv1 = s_invd[2 * c2 + 1];
      f32x2* adst = (f32x2*)(attn_out + (size_t)b * (Q_ * K_));
      f32x2* tdst = (f32x2*)(tattn_out + (size_t)b * (Q_ * K_));
      for (int row = r0; row < Q_; row += 16) {
        float ex = s_sc[row * 33 + 2 * c2];
        float ey = s_sc[row * 33 + 2 * c2 + 1];
        float ir = s_invrow[row];
        f32x2 av = { ex * ir, ey * ir };
        f32x2 tv2 = { m0 ? ex * inv0 : C197, m1 ? ey * inv1 : C197 };
        int o = row * 15 + c2;
        __builtin_nontemporal_store(av, &adst[o]);
        __builtin_nontemporal_store(tv2, &tdst[o]);
      }
    }
  }
}

// ---------------- K3: pooled PV (i2t): P_out[i,t,e] ----------------
__global__ __launch_bounds__(512) void pool_out_kernel(
    const float* __restrict__ A_sum, const float* __restrict__ ws_v,
    float* __restrict__ P_out)
{
  int bt = blockIdx.x;           // i*T + t
  int t = bt & 63;
  int tid = threadIdx.x;
  int h = tid >> 6, d = tid & 63;
  __shared__ float s_A[H_ * K_];
  if (tid < H_ * K_) s_A[tid] = A_sum[(size_t)bt * H_ * K_ + tid];
  __syncthreads();
  float a0 = 0.f, a1 = 0.f;
  #pragma unroll
  for (int kk = 0; kk < K_; kk += 2) {
    a0 = fmaf(s_A[h * K_ + kk],     ws_v[((size_t)(t * K_ + kk)     * H_ + h) * D_ + d], a0);
    a1 = fmaf(s_A[h * K_ + kk + 1], ws_v[((size_t)(t * K_ + kk + 1) * H_ + h) * D_ + d], a1);
  }
  P_out[(size_t)bt * E_ + tid] = (a0 + a1) * (1.0f / 197.0f);
}

// ---------------- K4: pooled (t2i): P_txt[i,t,e] ----------------
__global__ __launch_bounds__(512) void pool_text_kernel(
    const float* __restrict__ TA_sum, const float* __restrict__ ws_tv,
    float* __restrict__ P_txt)
{
  int bt = blockIdx.x;           // i*T + t
  int i = bt >> 6;
  int tid = threadIdx.x;
  int h = tid >> 6, d = tid & 63;
  __shared__ float s_TA[H_ * Q_];
  for (int idx = tid; idx < H_ * Q_; idx += 512) s_TA[idx] = TA_sum[(size_t)bt * H_ * Q_ + idx];
  __syncthreads();
  float a0 = 0.f, a1 = 0.f, a2 = 0.f, a3 = 0.f;
  int qq = 0;
  for (; qq + 4 <= Q_; qq += 4) {
    a0 = fmaf(s_TA[h * Q_ + qq + 0], ws_tv[((size_t)(i * Q_ + qq + 0) * H_ + h) * D_ + d], a0);
    a1 = fmaf(s_TA[h * Q_ + qq + 1], ws_tv[((size_t)(i * Q_ + qq + 1) * H_ + h) * D_ + d], a1);
    a2 = fmaf(s_TA[h * Q_ + qq + 2], ws_tv[((size_t)(i * Q_ + qq + 2) * H_ + h) * D_ + d], a2);
    a3 = fmaf(s_TA[h * Q_ + qq + 3], ws_tv[((size_t)(i * Q_ + qq + 3) * H_ + h) * D_ + d], a3);
  }
  for (; qq < Q_; ++qq)
    a0 = fmaf(s_TA[h * Q_ + qq], ws_tv[((size_t)(i * Q_ + qq) * H_ + h) * D_ + d], a0);
  P_txt[(size_t)bt * E_ + tid] = ((a0 + a1) + (a2 + a3)) * (1.0f / 30.0f);
}

// ---------------- K5: out = A @ W^T + bias (M=1024,N=512,K=512) ----------------
__global__ __launch_bounds__(256) void outproj_kernel(
    const float* __restrict__ A, const float* __restrict__ W,
    const float* __restrict__ bias, float* __restrict__ out)
{
  int r0 = blockIdx.x * 8;
  int eo = blockIdx.y * 256 + threadIdx.x;
  __shared__ float s_A[8][E_];   // 16 KB
  for (int idx = threadIdx.x; idx < 8 * E_; idx += 256)
    s_A[idx >> 9][idx & 511] = A[(size_t)(r0 + (idx >> 9)) * E_ + (idx & 511)];
  __syncthreads();
  float acc[8] = {};
  const float4* wrow = (const float4*)(W + (size_t)eo * E_);
  for (int e4 = 0; e4 < E_ / 4; ++e4) {
    float4 w4 = wrow[e4];
    #pragma unroll
    for (int r = 0; r < 8; ++r) {
      acc[r] = fmaf(s_A[r][e4 * 4 + 0], w4.x, acc[r]);
      acc[r] = fmaf(s_A[r][e4 * 4 + 1], w4.y, acc[r]);
      acc[r] = fmaf(s_A[r][e4 * 4 + 2], w4.z, acc[r]);
      acc[r] = fmaf(s_A[r][e4 * 4 + 3], w4.w, acc[r]);
    }
  }
  float bv = bias[eo];
  #pragma unroll
  for (int r = 0; r < 8; ++r) out[(size_t)(r0 + r) * E_ + eo] = acc[r] + bv;
}

extern "C" void kernel_launch(void* const* d_in, const int* in_sizes, int n_in,
                              void* d_out, int out_size, void* d_ws, size_t ws_size,
                              hipStream_t stream)
{
  const float* image      = (const float*)d_in[0];
  const float* text       = (const float*)d_in[1];
  const int*   tmask      = (const int*)d_in[2];
  const float* Wq         = (const float*)d_in[3];
  const float* Wk         = (const float*)d_in[4];
  const float* Wv         = (const float*)d_in[5];
  const float* W_out      = (const float*)d_in[6];
  const float* b_out      = (const float*)d_in[7];
  const float* Wtv        = (const float*)d_in[8];
  const float* W_out_text = (const float*)d_in[9];
  const float* b_out_text = (const float*)d_in[10];

  float* out = (float*)d_out;
  float* ws  = (float*)d_ws;

  const __hip_bfloat16* qbf = (const __hip_bfloat16*)(ws + OFF_QBF);
  const __hip_bfloat16* kbf = (const __hip_bfloat16*)(ws + OFF_KBF);
  float* v     = ws + OFF_V;
  float* tv    = ws + OFF_TV;
  float* Asum  = ws + OFF_ASUM;
  float* TAsum = ws + OFF_TASUM;
  float* Pout  = ws + OFF_POUT;
  float* Ptxt  = ws + OFF_PTXT;

  float* out_i2t = out;                                   // [I,T,E]
  float* out_t2i = out + (size_t)I_ * T_ * E_;            // [I,T,E]
  float* attn    = out + (size_t)2 * I_ * T_ * E_;        // [I,T,H,Q,K]
  float* tattn   = attn + (size_t)I_ * T_ * H_ * Q_ * K_; // [I,T,H,Q,K]

  proj_kernel<<<(I_*Q_)/4 + 2*((T_*K_)/4) + (I_*Q_)/4, 512, 0, stream>>>(image, text, Wq, Wk, Wv, Wtv, ws);
  attn_kernel<<<I_ * T_ * H_, 256, 0, stream>>>(qbf, kbf, tmask, attn, tattn, Asum, TAsum);
  pool_out_kernel<<<I_ * T_, 512, 0, stream>>>(Asum, v, Pout);
  pool_text_kernel<<<I_ * T_, 512, 0, stream>>>(TAsum, tv, Ptxt);
  outproj_kernel<<<dim3(128, 2), 256, 0, stream>>>(Pout, W_out, b_out, out_i2t);
  outproj_kernel<<<dim3(128, 2), 256, 0, stream>>>(Ptxt, W_out_text, b_out_text, out_t2i);
}